// Round 1
// baseline (110.434 us; speedup 1.0000x reference)
//
#include <hip/hip_runtime.h>
#include <math.h>

// Problem constants (B=8, N=M=4096, 3-D points, fp32)
#define BATCH   8
#define NPTS    4096
#define TOTAL   (BATCH * NPTS)      // 32768 points per array
#define THREADS 256
#define CHUNKS  8                   // split M-loop for occupancy: 2*128*8 = 2048 blocks
#define CHUNK   (NPTS / CHUNKS)     // 512 iterations per thread
#define PBLOCKS (TOTAL / THREADS)   // 128 point-blocks per direction
#define PB_PER_BATCH (NPTS / THREADS) // 16

// ws layout:
//   [0)                : scaled1, TOTAL float4   (-2x,-2y,-2z, ||p||^2)
//   [TOTAL*16)         : scaled2, TOTAL float4
//   [2*TOTAL*16)       : dist,    2*TOTAL float  (dist1 ++ dist2, as min accumulators)

__global__ __launch_bounds__(THREADS)
void pack_kernel(const float* __restrict__ a1, const float* __restrict__ a2,
                 float4* __restrict__ s1, float4* __restrict__ s2,
                 float* __restrict__ dist) {
    int i = blockIdx.x * THREADS + threadIdx.x;   // 0 .. 2*TOTAL-1
    const float* src;
    float4* dst;
    int j;
    if (i < TOTAL) { src = a1; dst = s1; j = i; }
    else           { src = a2; dst = s2; j = i - TOTAL; }
    float x = src[3 * j + 0];
    float y = src[3 * j + 1];
    float z = src[3 * j + 2];
    float sq = fmaf(x, x, fmaf(y, y, z * z));
    dst[j] = make_float4(-2.0f * x, -2.0f * y, -2.0f * z, sq);
    dist[i] = __builtin_inff();   // min-accumulator init (+inf); ws is poisoned each call
}

// d(p1, p2) = ||p1||^2 + ||p2||^2 - 2 p1.p2
//           = fma(q.x, x1, fma(q.y, y1, fma(q.z, z1, q.w))) + sq1
// where q = (-2x2, -2y2, -2z2, ||p2||^2) and (x1,y1,z1,sq1) are the raw
// self-point coords (recovered from its scaled form by *-0.5, exact).
// max(d,0) commutes with min_m, so clamp once at the end.
__global__ __launch_bounds__(THREADS, 8)
void chamfer_min_kernel(const float4* __restrict__ s1, const float4* __restrict__ s2,
                        unsigned int* __restrict__ dist) {
    const int bid   = blockIdx.x;                 // 0 .. 2*PBLOCKS*CHUNKS-1
    const int dir   = bid / (PBLOCKS * CHUNKS);   // 0: a1->a2 mins, 1: a2->a1 mins
    const int r     = bid % (PBLOCKS * CHUNKS);
    const int pb    = r / CHUNKS;                 // point-block 0..127
    const int chunk = r % CHUNKS;                 // m-chunk 0..7
    const int batch = pb / PB_PER_BATCH;          // wave-uniform, from blockIdx only

    const float4* __restrict__ self  = dir ? s2 : s1;
    const float4* __restrict__ other = dir ? s1 : s2;

    const int i = pb * THREADS + threadIdx.x;     // my point index (0..TOTAL-1)
    float4 p = self[i];
    const float x1 = -0.5f * p.x;
    const float y1 = -0.5f * p.y;
    const float z1 = -0.5f * p.z;
    const float sq1 = p.w;

    // block-uniform pointer -> inner loads are wave-uniform (scalar-load friendly)
    const float4* __restrict__ q = other + batch * NPTS + chunk * CHUNK;

    float m0 = __builtin_inff(), m1 = __builtin_inff();
    float m2 = __builtin_inff(), m3 = __builtin_inff();
    #pragma unroll 2
    for (int j = 0; j < CHUNK; j += 4) {
        float4 q0 = q[j + 0];
        float4 q1 = q[j + 1];
        float4 q2 = q[j + 2];
        float4 q3 = q[j + 3];
        float d0 = fmaf(q0.x, x1, fmaf(q0.y, y1, fmaf(q0.z, z1, q0.w))) + sq1;
        float d1 = fmaf(q1.x, x1, fmaf(q1.y, y1, fmaf(q1.z, z1, q1.w))) + sq1;
        float d2 = fmaf(q2.x, x1, fmaf(q2.y, y1, fmaf(q2.z, z1, q2.w))) + sq1;
        float d3 = fmaf(q3.x, x1, fmaf(q3.y, y1, fmaf(q3.z, z1, q3.w))) + sq1;
        m0 = fminf(m0, d0);
        m1 = fminf(m1, d1);
        m2 = fminf(m2, d2);
        m3 = fminf(m3, d3);
    }
    float dmin = fminf(fminf(m0, m1), fminf(m2, m3));
    dmin = fmaxf(dmin, 0.0f);   // clamp; also guarantees non-negative for uint-ordered atomicMin
    atomicMin(dist + dir * TOTAL + i, __float_as_uint(dmin));
}

__global__ __launch_bounds__(1024)
void reduce_kernel(const float* __restrict__ dist, float* __restrict__ out) {
    // mean(dist1) + mean(dist2) = (sum over all 2*TOTAL mins) / TOTAL
    float s = 0.0f;
    for (int i = threadIdx.x; i < 2 * TOTAL; i += 1024) s += dist[i];
    #pragma unroll
    for (int off = 32; off > 0; off >>= 1) s += __shfl_down(s, off, 64);
    __shared__ float wsum[16];
    int wave = threadIdx.x >> 6;
    if ((threadIdx.x & 63) == 0) wsum[wave] = s;
    __syncthreads();
    if (threadIdx.x < 16) {
        float v = wsum[threadIdx.x];
        #pragma unroll
        for (int off = 8; off > 0; off >>= 1) v += __shfl_down(v, off, 16);
        if (threadIdx.x == 0) out[0] = v * (1.0f / (float)TOTAL);
    }
}

extern "C" void kernel_launch(void* const* d_in, const int* in_sizes, int n_in,
                              void* d_out, int out_size, void* d_ws, size_t ws_size,
                              hipStream_t stream) {
    const float* a1 = (const float*)d_in[0];
    const float* a2 = (const float*)d_in[1];
    float* out = (float*)d_out;

    char* ws = (char*)d_ws;
    float4* s1  = (float4*)(ws);
    float4* s2  = (float4*)(ws + (size_t)TOTAL * sizeof(float4));
    float*  dist = (float*)(ws + 2 * (size_t)TOTAL * sizeof(float4));

    // 1) pack + init min accumulators
    pack_kernel<<<(2 * TOTAL) / THREADS, THREADS, 0, stream>>>(a1, a2, s1, s2, dist);
    // 2) pairwise min, both directions fused in one grid (2048 blocks, full occupancy)
    chamfer_min_kernel<<<2 * PBLOCKS * CHUNKS, THREADS, 0, stream>>>(s1, s2, (unsigned int*)dist);
    // 3) final mean
    reduce_kernel<<<1, 1024, 0, stream>>>(dist, out);
}